// Round 2
// baseline (1029.475 us; speedup 1.0000x reference)
//
#include <hip/hip_runtime.h>
#include <float.h>

// Problem constants (from reference file)
constexpr int C    = 512;          // DIM_CODES
constexpr int K    = 512;          // DICT_SIZE
constexpr int E    = 16;           // EMBED_DIM
constexpr int B    = 512;          // BATCH
constexpr int ROWS = 128;          // batches per block
constexpr int MUS  = C * E;        // 8192, mu row stride

// native vector type for nontemporal 16B stores (HIP float4 is a class type
// and is rejected by __builtin_nontemporal_store)
typedef float f32x4 __attribute__((ext_vector_type(4)));

// Each block: one code-dim c, 128 batch rows. 4 waves; each wave processes
// TWO batch rows per iteration (32 rows/wave total). The wave holds the FULL
// 512x16 dict slice for c in registers: lane holds k = lane + 64*i, i in
// [0,8) => 128 VGPRs of dict data, zero LDS traffic for the inner product.
//
// v2 changes vs the 695.7us baseline (latency-bound diagnosis):
//  - 2 independent rows in flight per wave-iteration (hides shfl latency)
//  - per-lane runner-up folded into the distance loop (no dist_v array,
//    no second butterfly)
//  - wave argmin = value-only __shfl_xor min butterfly (6 DS ops) +
//    __ballot/__ffsll + one __shfl for the index; cross-lane ties always
//    satisfy the 1e-3 near-tie trigger so the fp64 path resolves them with
//    first-index semantics => outputs bit-identical to the verified kernel
//  - nontemporal stores for the write-only oh/z/zq streams
__launch_bounds__(256, 2)
__global__ void vq_kernel(const float* __restrict__ mu,
                          const float* __restrict__ dict,
                          float* __restrict__ z,
                          float* __restrict__ zq,
                          float* __restrict__ oh)
{
    const int c    = blockIdx.x;
    const int b0   = blockIdx.y * ROWS;
    const int tid  = threadIdx.x;
    const int lane = tid & 63;
    const int wave = tid >> 6;

    __shared__ float mu_s[ROWS][E];    // 8 KB

    const float* __restrict__ dbase = dict + (size_t)c * K * E;

    // ---- dict slice -> registers, plus per-code squared norms
    float4 dv[8][4];
    float  nrm[8];
#pragma unroll
    for (int i = 0; i < 8; ++i) {
        const int k = lane + 64 * i;
        const float4* p = reinterpret_cast<const float4*>(dbase + k * E);
        dv[i][0] = p[0]; dv[i][1] = p[1]; dv[i][2] = p[2]; dv[i][3] = p[3];
        float s = dv[i][0].x * dv[i][0].x;
        s = fmaf(dv[i][0].y, dv[i][0].y, s);
        s = fmaf(dv[i][0].z, dv[i][0].z, s);
        s = fmaf(dv[i][0].w, dv[i][0].w, s);
#pragma unroll
        for (int t = 1; t < 4; ++t) {
            s = fmaf(dv[i][t].x, dv[i][t].x, s);
            s = fmaf(dv[i][t].y, dv[i][t].y, s);
            s = fmaf(dv[i][t].z, dv[i][t].z, s);
            s = fmaf(dv[i][t].w, dv[i][t].w, s);
        }
        nrm[i] = s;
    }

    // ---- stage the 128x16 mu sub-block for this (c, chunk) into LDS
    {
        const int r = tid >> 2, q = tid & 3;
#pragma unroll
        for (int rep = 0; rep < 2; ++rep) {
            const int row = r + rep * 64;
            const float4* p = reinterpret_cast<const float4*>(
                mu + (size_t)(b0 + row) * MUS + c * E);
            reinterpret_cast<float4*>(&mu_s[row][0])[q] = p[q];
        }
    }
    __syncthreads();

    for (int j = 0; j < ROWS / 8; ++j) {       // 16 iterations, 2 rows each
        int    bl[2];
        float4 m[2][4];
        float  nmu[2], bd[2], sec[2];
        int    bk[2];

        // ---- per-row: distances + per-lane argmin AND per-lane runner-up
#pragma unroll
        for (int pr = 0; pr < 2; ++pr) {
            bl[pr] = wave + 8 * j + 4 * pr;

            // broadcast-read the 16-float query (same addr across lanes: free)
#pragma unroll
            for (int t = 0; t < 4; ++t)
                m[pr][t] = reinterpret_cast<const float4*>(&mu_s[bl[pr]][0])[t];

            float nm = m[pr][0].x * m[pr][0].x;
            nm = fmaf(m[pr][0].y, m[pr][0].y, nm);
            nm = fmaf(m[pr][0].z, m[pr][0].z, nm);
            nm = fmaf(m[pr][0].w, m[pr][0].w, nm);
#pragma unroll
            for (int t = 1; t < 4; ++t) {
                nm = fmaf(m[pr][t].x, m[pr][t].x, nm);
                nm = fmaf(m[pr][t].y, m[pr][t].y, nm);
                nm = fmaf(m[pr][t].z, m[pr][t].z, nm);
                nm = fmaf(m[pr][t].w, m[pr][t].w, nm);
            }
            nmu[pr] = nm;

            float bdl = FLT_MAX, secl = FLT_MAX;
            int   bkl = K;
#pragma unroll
            for (int i = 0; i < 8; ++i) {
                float acc = dv[i][0].x * m[pr][0].x;
                acc = fmaf(dv[i][0].y, m[pr][0].y, acc);
                acc = fmaf(dv[i][0].z, m[pr][0].z, acc);
                acc = fmaf(dv[i][0].w, m[pr][0].w, acc);
#pragma unroll
                for (int t = 1; t < 4; ++t) {
                    acc = fmaf(dv[i][t].x, m[pr][t].x, acc);
                    acc = fmaf(dv[i][t].y, m[pr][t].y, acc);
                    acc = fmaf(dv[i][t].z, m[pr][t].z, acc);
                    acc = fmaf(dv[i][t].w, m[pr][t].w, acc);
                }
                // identical rounding to the verified kernel
                const float dist = fmaf(-2.0f, acc, nm + nrm[i]);
                const int   k    = lane + 64 * i;
                const bool  lt   = dist < bdl;           // ascending k =>
                secl = lt ? bdl : fminf(secl, dist);     // first-index ties
                bdl  = lt ? dist : bdl;
                bkl  = lt ? k : bkl;
            }
            bd[pr] = bdl; sec[pr] = secl; bk[pr] = bkl;
        }

        // ---- wave min: value-only xor butterflies, 2 rows interleaved
        float w0 = bd[0], w1 = bd[1];
#pragma unroll
        for (int off = 32; off; off >>= 1) {
            w0 = fminf(w0, __shfl_xor(w0, off));
            w1 = fminf(w1, __shfl_xor(w1, off));
        }
        const float w[2] = { w0, w1 };

#pragma unroll
        for (int pr = 0; pr < 2; ++pr) {
            const int bl_ = bl[pr];
            const int b   = b0 + bl_;

            // index recovery: first lane holding the min value
            const unsigned long long mask = __ballot(bd[pr] == w[pr]);
            const int lane0 = __ffsll(mask) - 1;
            int best_k = __shfl(bk[pr], lane0);

            // near-tie trigger == (global runner-up - best) < 1e-3.
            // global runner-up = min over lanes of (winner lane ? its own
            // 2nd-best : its best); cross-lane exact ties give cand == w
            // and always trigger, so ballot's lane-order tie choice never
            // reaches the output.
            const float cand = (lane == lane0) ? sec[pr] : bd[pr];
            if (__any(cand < w[pr] + 1e-3f)) {
                // ---- rare exact path: fp64 re-evaluation (wave-parallel)
                double nmuD = 0.0;
#pragma unroll
                for (int t = 0; t < 4; ++t) {
                    nmuD += (double)m[pr][t].x * m[pr][t].x
                          + (double)m[pr][t].y * m[pr][t].y
                          + (double)m[pr][t].z * m[pr][t].z
                          + (double)m[pr][t].w * m[pr][t].w;
                }
                double bD = DBL_MAX;
                int    bK = K;
#pragma unroll
                for (int i = 0; i < 8; ++i) {
                    double nd = 0.0, dt = 0.0;
#pragma unroll
                    for (int t = 0; t < 4; ++t) {
                        nd += (double)dv[i][t].x * dv[i][t].x
                            + (double)dv[i][t].y * dv[i][t].y
                            + (double)dv[i][t].z * dv[i][t].z
                            + (double)dv[i][t].w * dv[i][t].w;
                        dt += (double)dv[i][t].x * m[pr][t].x
                            + (double)dv[i][t].y * m[pr][t].y
                            + (double)dv[i][t].z * m[pr][t].z
                            + (double)dv[i][t].w * m[pr][t].w;
                    }
                    const double dist = nmuD + nd - 2.0 * dt;
                    const int k = lane + 64 * i;
                    if (dist < bD) { bD = dist; bK = k; }
                }
#pragma unroll
                for (int off = 32; off; off >>= 1) {
                    const double od = __shfl_down(bD, off);
                    const int    ok = __shfl_down(bK, off);
                    if (od < bD || (od == bD && ok < bK)) { bD = od; bK = ok; }
                }
                best_k = __shfl(bK, 0);
            }

            // ---- one_hot row: 512 floats, two coalesced 16B nt-stores
            float* ohp = oh + ((size_t)b * C + c) * K;
#pragma unroll
            for (int h = 0; h < 2; ++h) {
                const int kb = h * 256 + lane * 4;
                f32x4 v;
                v.x = (kb + 0 == best_k) ? 1.0f : 0.0f;
                v.y = (kb + 1 == best_k) ? 1.0f : 0.0f;
                v.z = (kb + 2 == best_k) ? 1.0f : 0.0f;
                v.w = (kb + 3 == best_k) ? 1.0f : 0.0f;
                __builtin_nontemporal_store(v, reinterpret_cast<f32x4*>(ohp + kb));
            }

            // ---- z_embed and z = mu + (zq - mu), fp32 op-for-op like ref
            if (lane < E) {
                const float dq = dbase[best_k * E + lane];   // L2-hot
                const float mm = mu_s[bl_][lane];
                const size_t o = (size_t)b * MUS + (size_t)c * E + lane;
                __builtin_nontemporal_store(dq, zq + o);
                __builtin_nontemporal_store(mm + (dq - mm), z + o);
            }
        }
    }
}

extern "C" void kernel_launch(void* const* d_in, const int* in_sizes, int n_in,
                              void* d_out, int out_size, void* d_ws, size_t ws_size,
                              hipStream_t stream)
{
    const float* mu   = (const float*)d_in[0];
    const float* dict = (const float*)d_in[1];

    float* z  = (float*)d_out;                 // (B, C*E)
    float* zq = z  + (size_t)B * C * E;        // (B, C*E)
    float* oh = zq + (size_t)B * C * E;        // (B, C, K)

    dim3 grid(C, B / ROWS);
    vq_kernel<<<grid, 256, 0, stream>>>(mu, dict, z, zq, oh);
}

// Round 3
// 751.134 us; speedup vs baseline: 1.3706x; 1.3706x over previous
//
#include <hip/hip_runtime.h>
#include <float.h>

// Problem constants (from reference file)
constexpr int C    = 512;          // DIM_CODES
constexpr int K    = 512;          // DICT_SIZE
constexpr int E    = 16;           // EMBED_DIM
constexpr int B    = 512;          // BATCH
constexpr int ROWS = 128;          // batches per block
constexpr int MUS  = C * E;        // 8192, mu row stride

// Each block: one code-dim c, 128 batch rows. 4 waves; each wave processes
// one batch row per pipeline stage (32 rows/wave). The wave holds the FULL
// 512x16 dict slice for c in registers: lane holds k = lane + 64*i, i in
// [0,8) => 128 VGPRs of dict data, zero LDS traffic for the inner product.
//
// v3 (post-mortem of v2's 585us spill regression, VGPR_Count=128 +
// 345MB excess FETCH = scratch traffic):
//  - software pipeline with MINIMAL carried state: compute(row j+1)
//    overlaps emit(row j); carried state is only {bd, sec, bk} (3 VGPRs).
//    The query m[] is DEAD after the distance loop: the rare fp64 path and
//    the z/zq epilogue reload it from mu_s (same bits).
//  - reduce/tie logic identical to the harness-verified v2 (absmax 0.0):
//    value-only __shfl_xor min butterfly + ballot/first-lane index; any
//    cross-lane exact tie makes cand == w and triggers the fp64 re-eval,
//    which applies first-index semantics.
//  - plain (non-nt) stores, as in the 695.7us baseline.
__launch_bounds__(256, 2)
__global__ void vq_kernel(const float* __restrict__ mu,
                          const float* __restrict__ dict,
                          float* __restrict__ z,
                          float* __restrict__ zq,
                          float* __restrict__ oh)
{
    const int c    = blockIdx.x;
    const int b0   = blockIdx.y * ROWS;
    const int tid  = threadIdx.x;
    const int lane = tid & 63;
    const int wave = tid >> 6;

    __shared__ float mu_s[ROWS][E];    // 8 KB

    const float* __restrict__ dbase = dict + (size_t)c * K * E;

    // ---- dict slice -> registers, plus per-code squared norms
    float4 dv[8][4];
    float  nrm[8];
#pragma unroll
    for (int i = 0; i < 8; ++i) {
        const int k = lane + 64 * i;
        const float4* p = reinterpret_cast<const float4*>(dbase + k * E);
        dv[i][0] = p[0]; dv[i][1] = p[1]; dv[i][2] = p[2]; dv[i][3] = p[3];
        float s = dv[i][0].x * dv[i][0].x;
        s = fmaf(dv[i][0].y, dv[i][0].y, s);
        s = fmaf(dv[i][0].z, dv[i][0].z, s);
        s = fmaf(dv[i][0].w, dv[i][0].w, s);
#pragma unroll
        for (int t = 1; t < 4; ++t) {
            s = fmaf(dv[i][t].x, dv[i][t].x, s);
            s = fmaf(dv[i][t].y, dv[i][t].y, s);
            s = fmaf(dv[i][t].z, dv[i][t].z, s);
            s = fmaf(dv[i][t].w, dv[i][t].w, s);
        }
        nrm[i] = s;
    }

    // ---- stage the 128x16 mu sub-block for this (c, chunk) into LDS
    {
        const int r = tid >> 2, q = tid & 3;
#pragma unroll
        for (int rep = 0; rep < 2; ++rep) {
            const int row = r + rep * 64;
            const float4* p = reinterpret_cast<const float4*>(
                mu + (size_t)(b0 + row) * MUS + c * E);
            reinterpret_cast<float4*>(&mu_s[row][0])[q] = p[q];
        }
    }
    __syncthreads();

    // ---- distances + per-lane argmin AND per-lane runner-up for one row.
    // Query m[] is loop-local (dead after this returns): tiny pipeline state.
    auto compute_row = [&](int bl, float& obd, float& osec, int& obk) {
        float4 m[4];
#pragma unroll
        for (int t = 0; t < 4; ++t)
            m[t] = reinterpret_cast<const float4*>(&mu_s[bl][0])[t];

        float nm = m[0].x * m[0].x;
        nm = fmaf(m[0].y, m[0].y, nm);
        nm = fmaf(m[0].z, m[0].z, nm);
        nm = fmaf(m[0].w, m[0].w, nm);
#pragma unroll
        for (int t = 1; t < 4; ++t) {
            nm = fmaf(m[t].x, m[t].x, nm);
            nm = fmaf(m[t].y, m[t].y, nm);
            nm = fmaf(m[t].z, m[t].z, nm);
            nm = fmaf(m[t].w, m[t].w, nm);
        }

        float bdl = FLT_MAX, secl = FLT_MAX;
        int   bkl = K;
#pragma unroll
        for (int i = 0; i < 8; ++i) {
            float acc = dv[i][0].x * m[0].x;
            acc = fmaf(dv[i][0].y, m[0].y, acc);
            acc = fmaf(dv[i][0].z, m[0].z, acc);
            acc = fmaf(dv[i][0].w, m[0].w, acc);
#pragma unroll
            for (int t = 1; t < 4; ++t) {
                acc = fmaf(dv[i][t].x, m[t].x, acc);
                acc = fmaf(dv[i][t].y, m[t].y, acc);
                acc = fmaf(dv[i][t].z, m[t].z, acc);
                acc = fmaf(dv[i][t].w, m[t].w, acc);
            }
            // identical rounding to the verified kernel
            const float dist = fmaf(-2.0f, acc, nm + nrm[i]);
            const int   k    = lane + 64 * i;
            const bool  lt   = dist < bdl;           // ascending k =>
            secl = lt ? bdl : fminf(secl, dist);     // first-index ties
            bdl  = lt ? dist : bdl;
            bkl  = lt ? k : bkl;
        }
        obd = bdl; osec = secl; obk = bkl;
    };

    // ---- wave argmin + outputs for one row (state: bd, sec, bk only)
    auto emit_row = [&](int bl_, float bd, float sec, int bk) {
        const int b = b0 + bl_;

        float w = bd;
#pragma unroll
        for (int off = 32; off; off >>= 1)
            w = fminf(w, __shfl_xor(w, off));

        // index recovery: first lane holding the min value
        const unsigned long long mask = __ballot(bd == w);
        const int lane0 = __ffsll(mask) - 1;
        int best_k = __shfl(bk, lane0);

        // near-tie trigger == (global runner-up - best) < 1e-3.
        // cross-lane exact ties give cand == w and always trigger, so
        // ballot's lane-order tie choice never reaches the output.
        const float cand = (lane == lane0) ? sec : bd;
        if (__any(cand < w + 1e-3f)) {
            // ---- rare exact path: fp64 re-eval; reload query from LDS
            float mf[E];
#pragma unroll
            for (int t = 0; t < E; ++t) mf[t] = mu_s[bl_][t];
            double nmuD = 0.0;
#pragma unroll
            for (int t = 0; t < E; ++t) nmuD += (double)mf[t] * mf[t];

            double bD = DBL_MAX;
            int    bK = K;
#pragma unroll
            for (int i = 0; i < 8; ++i) {
                double nd = 0.0, dt = 0.0;
#pragma unroll
                for (int t = 0; t < 4; ++t) {
                    nd += (double)dv[i][t].x * dv[i][t].x
                        + (double)dv[i][t].y * dv[i][t].y
                        + (double)dv[i][t].z * dv[i][t].z
                        + (double)dv[i][t].w * dv[i][t].w;
                    dt += (double)dv[i][t].x * mf[4 * t + 0]
                        + (double)dv[i][t].y * mf[4 * t + 1]
                        + (double)dv[i][t].z * mf[4 * t + 2]
                        + (double)dv[i][t].w * mf[4 * t + 3];
                }
                const double dist = nmuD + nd - 2.0 * dt;
                const int k = lane + 64 * i;
                if (dist < bD) { bD = dist; bK = k; }
            }
#pragma unroll
            for (int off = 32; off; off >>= 1) {
                const double od = __shfl_down(bD, off);
                const int    ok = __shfl_down(bK, off);
                if (od < bD || (od == bD && ok < bK)) { bD = od; bK = ok; }
            }
            best_k = __shfl(bK, 0);
        }

        // ---- one_hot row: 512 floats, two coalesced float4 stores per lane
        float* ohp = oh + ((size_t)b * C + c) * K;
#pragma unroll
        for (int h = 0; h < 2; ++h) {
            const int kb = h * 256 + lane * 4;
            float4 v;
            v.x = (kb + 0 == best_k) ? 1.0f : 0.0f;
            v.y = (kb + 1 == best_k) ? 1.0f : 0.0f;
            v.z = (kb + 2 == best_k) ? 1.0f : 0.0f;
            v.w = (kb + 3 == best_k) ? 1.0f : 0.0f;
            *reinterpret_cast<float4*>(ohp + kb) = v;
        }

        // ---- z_embed and z = mu + (zq - mu), fp32 op-for-op like reference
        if (lane < E) {
            const float dq = dbase[best_k * E + lane];   // L2-hot
            const float mm = mu_s[bl_][lane];
            const size_t o = (size_t)b * MUS + (size_t)c * E + lane;
            zq[o] = dq;
            z[o]  = mm + (dq - mm);
        }
    };

    // ---- software pipeline: compute(row j+1) overlaps emit(row j).
    // Carried state per row: {bd, sec, bk} = 3 VGPRs.
    {
        int   pbl = wave;
        float pbd, psec;
        int   pbk;
        compute_row(pbl, pbd, psec, pbk);

        for (int j = 1; j < ROWS / 4; ++j) {
            const int cbl = wave + 4 * j;
            float cbd, csec;
            int   cbk;
            compute_row(cbl, cbd, csec, cbk);   // ~170 independent FMAs...
            emit_row(pbl, pbd, psec, pbk);      // ...hide this shfl chain
            pbl = cbl; pbd = cbd; psec = csec; pbk = cbk;
        }
        emit_row(pbl, pbd, psec, pbk);
    }
}

extern "C" void kernel_launch(void* const* d_in, const int* in_sizes, int n_in,
                              void* d_out, int out_size, void* d_ws, size_t ws_size,
                              hipStream_t stream)
{
    const float* mu   = (const float*)d_in[0];
    const float* dict = (const float*)d_in[1];

    float* z  = (float*)d_out;                 // (B, C*E)
    float* zq = z  + (size_t)B * C * E;        // (B, C*E)
    float* oh = zq + (size_t)B * C * E;        // (B, C, K)

    dim3 grid(C, B / ROWS);
    vq_kernel<<<grid, 256, 0, stream>>>(mu, dict, z, zq, oh);
}

// Round 4
// 701.541 us; speedup vs baseline: 1.4674x; 1.0707x over previous
//
#include <hip/hip_runtime.h>
#include <float.h>

// Problem constants (from reference file)
constexpr int C    = 512;          // DIM_CODES
constexpr int K    = 512;          // DICT_SIZE
constexpr int E    = 16;           // EMBED_DIM
constexpr int B    = 512;          // BATCH
constexpr int RB   = 256;          // batch rows per block (1 per lane)
constexpr int MUS  = C * E;        // 8192, mu row stride

// v4 — lane-per-row layout (post-mortem of v2 spill / v3 neutral):
// the wave-cooperative argmin's dependent shuffle chain was the bottleneck
// and could not be hidden (2 waves/SIMD, 128 dict VGPRs). Now each LANE owns
// one batch row and serially scans all K codes; dict is wave-UNIFORM per k,
// staged in LDS and read via broadcast ds_read_b128. Hot loop has zero
// cross-lane ops; argmin is a per-lane strict-< update (first-index ties).
// LDS 34KB -> 4 blocks/CU; all waves resident; VGPR ~70.
//
// Numerics identical to the harness-verified kernels (absmax 0.0):
//  - same fma chains for nm, acc, dist = fmaf(-2, acc, nm + nrm[k])
//  - per-lane sec == global runner-up; trigger sec < bd + 1e-3
//  - rare near-ties resolved by the SAME wave-cooperative fp64 re-scan
__launch_bounds__(256, 4)
__global__ void vq_kernel(const float* __restrict__ mu,
                          const float* __restrict__ dict,
                          float* __restrict__ z,
                          float* __restrict__ zq,
                          float* __restrict__ oh)
{
    const int c    = blockIdx.x;
    const int b0   = blockIdx.y * RB;
    const int tid  = threadIdx.x;
    const int lane = tid & 63;
    const int wave = tid >> 6;

    __shared__ __align__(16) float dict_s[K * E];   // 32 KB
    __shared__ float nrm_s[K];                      // 2 KB

    const float* __restrict__ dbase = dict + (size_t)c * K * E;

    // ---- stage dict slice + per-code squared norms (same fma order as
    // the verified kernel's nrm computation)
#pragma unroll
    for (int rep = 0; rep < 2; ++rep) {
        const int k = tid + rep * 256;
        const float4* p = reinterpret_cast<const float4*>(dbase + k * E);
        const float4 d0 = p[0], d1 = p[1], d2 = p[2], d3 = p[3];
        float s = d0.x * d0.x;
        s = fmaf(d0.y, d0.y, s); s = fmaf(d0.z, d0.z, s); s = fmaf(d0.w, d0.w, s);
        s = fmaf(d1.x, d1.x, s); s = fmaf(d1.y, d1.y, s);
        s = fmaf(d1.z, d1.z, s); s = fmaf(d1.w, d1.w, s);
        s = fmaf(d2.x, d2.x, s); s = fmaf(d2.y, d2.y, s);
        s = fmaf(d2.z, d2.z, s); s = fmaf(d2.w, d2.w, s);
        s = fmaf(d3.x, d3.x, s); s = fmaf(d3.y, d3.y, s);
        s = fmaf(d3.z, d3.z, s); s = fmaf(d3.w, d3.w, s);
        float4* q4 = reinterpret_cast<float4*>(&dict_s[k * E]);
        q4[0] = d0; q4[1] = d1; q4[2] = d2; q4[3] = d3;
        nrm_s[k] = s;
    }
    __syncthreads();

    // ---- this lane's query row: 64B contiguous from global (L2-absorbed)
    const int myrow = (wave << 6) + lane;
    const float* __restrict__ mrow = mu + (size_t)(b0 + myrow) * MUS + c * E;
    float4 m0, m1, m2, m3;
    {
        const float4* p = reinterpret_cast<const float4*>(mrow);
        m0 = p[0]; m1 = p[1]; m2 = p[2]; m3 = p[3];
    }
    float nm = m0.x * m0.x;
    nm = fmaf(m0.y, m0.y, nm); nm = fmaf(m0.z, m0.z, nm); nm = fmaf(m0.w, m0.w, nm);
    nm = fmaf(m1.x, m1.x, nm); nm = fmaf(m1.y, m1.y, nm);
    nm = fmaf(m1.z, m1.z, nm); nm = fmaf(m1.w, m1.w, nm);
    nm = fmaf(m2.x, m2.x, nm); nm = fmaf(m2.y, m2.y, nm);
    nm = fmaf(m2.z, m2.z, nm); nm = fmaf(m2.w, m2.w, nm);
    nm = fmaf(m3.x, m3.x, nm); nm = fmaf(m3.y, m3.y, nm);
    nm = fmaf(m3.z, m3.z, nm); nm = fmaf(m3.w, m3.w, nm);

    // ---- serial scan over all K codes: zero cross-lane ops.
    // dict/nrm reads are wave-uniform -> LDS broadcast, no bank conflicts.
    float bd = FLT_MAX, sec = FLT_MAX;
    int   bk = K;
    const float4* __restrict__ ds4 = reinterpret_cast<const float4*>(dict_s);
#pragma unroll 4
    for (int k = 0; k < K; ++k) {
        const float4 d0 = ds4[k * 4 + 0];
        const float4 d1 = ds4[k * 4 + 1];
        const float4 d2 = ds4[k * 4 + 2];
        const float4 d3 = ds4[k * 4 + 3];
        float acc = d0.x * m0.x;
        acc = fmaf(d0.y, m0.y, acc); acc = fmaf(d0.z, m0.z, acc); acc = fmaf(d0.w, m0.w, acc);
        acc = fmaf(d1.x, m1.x, acc); acc = fmaf(d1.y, m1.y, acc);
        acc = fmaf(d1.z, m1.z, acc); acc = fmaf(d1.w, m1.w, acc);
        acc = fmaf(d2.x, m2.x, acc); acc = fmaf(d2.y, m2.y, acc);
        acc = fmaf(d2.z, m2.z, acc); acc = fmaf(d2.w, m2.w, acc);
        acc = fmaf(d3.x, m3.x, acc); acc = fmaf(d3.y, m3.y, acc);
        acc = fmaf(d3.z, m3.z, acc); acc = fmaf(d3.w, m3.w, acc);
        // identical rounding to the verified kernel
        const float dist = fmaf(-2.0f, acc, nm + nrm_s[k]);
        const bool  lt   = dist < bd;            // ascending k =>
        sec = lt ? bd : fminf(sec, dist);        // first-index ties
        bd  = lt ? dist : bd;
        bk  = lt ? k : bk;
    }

    // ---- rare near-tie path: wave-cooperative fp64 re-scan per flagged row.
    // ballot is wave-uniform -> uniform loop, all lanes participate.
    unsigned long long trig = __ballot(sec < bd + 1e-3f);
    while (trig) {
        const int r = __ffsll(trig) - 1;
        trig &= trig - 1;
        const int row = (wave << 6) + r;
        const float* __restrict__ qrow = mu + (size_t)(b0 + row) * MUS + c * E;

        double nmuD = 0.0;
#pragma unroll
        for (int t = 0; t < E; ++t) {
            const double mt = (double)qrow[t];
            nmuD += mt * mt;
        }
        double bD = DBL_MAX;
        int    bK = K;
#pragma unroll
        for (int i = 0; i < 8; ++i) {
            const int k = lane + 64 * i;
            const float* dk = &dict_s[k * E];
            double nd = 0.0, dt = 0.0;
#pragma unroll
            for (int t = 0; t < 4; ++t) {
                const double dx = dk[4 * t + 0], dy = dk[4 * t + 1];
                const double dz = dk[4 * t + 2], dw = dk[4 * t + 3];
                const double mx = qrow[4 * t + 0], my = qrow[4 * t + 1];
                const double mz = qrow[4 * t + 2], mw = qrow[4 * t + 3];
                nd += dx * dx + dy * dy + dz * dz + dw * dw;
                dt += dx * mx + dy * my + dz * mz + dw * mw;
            }
            const double dist = nmuD + nd - 2.0 * dt;
            if (dist < bD) { bD = dist; bK = k; }
        }
#pragma unroll
        for (int off = 32; off; off >>= 1) {
            const double od = __shfl_down(bD, off);
            const int    ok = __shfl_down(bK, off);
            if (od < bD || (od == bD && ok < bK)) { bD = od; bK = ok; }
        }
        const int kwin = __shfl(bK, 0);
        if (lane == r) bk = kwin;
    }

    // ---- store phase: broadcast each lane's winner, write coalesced.
    // Short dependence chains, streams stores at full rate.
#pragma unroll 4
    for (int r = 0; r < 64; ++r) {
        const int kk  = __shfl(bk, r);
        const int row = (wave << 6) + r;
        const int b   = b0 + row;

        // one_hot row: 512 floats, two coalesced float4 stores per lane
        float* ohp = oh + ((size_t)b * C + c) * K;
#pragma unroll
        for (int h = 0; h < 2; ++h) {
            const int kb = h * 256 + lane * 4;
            float4 v;
            v.x = (kb + 0 == kk) ? 1.0f : 0.0f;
            v.y = (kb + 1 == kk) ? 1.0f : 0.0f;
            v.z = (kb + 2 == kk) ? 1.0f : 0.0f;
            v.w = (kb + 3 == kk) ? 1.0f : 0.0f;
            *reinterpret_cast<float4*>(ohp + kb) = v;
        }

        // z_embed and z = mu + (zq - mu), fp32 op-for-op like reference
        if (lane < E) {
            const float dq = dict_s[kk * E + lane];
            const float mm = mu[(size_t)b * MUS + (size_t)c * E + lane]; // L1/L2-hot
            const size_t o = (size_t)b * MUS + (size_t)c * E + lane;
            zq[o] = dq;
            z[o]  = mm + (dq - mm);
        }
    }
}

extern "C" void kernel_launch(void* const* d_in, const int* in_sizes, int n_in,
                              void* d_out, int out_size, void* d_ws, size_t ws_size,
                              hipStream_t stream)
{
    const float* mu   = (const float*)d_in[0];
    const float* dict = (const float*)d_in[1];

    float* z  = (float*)d_out;                 // (B, C*E)
    float* zq = z  + (size_t)B * C * E;        // (B, C*E)
    float* oh = zq + (size_t)B * C * E;        // (B, C, K)

    dim3 grid(C, B / RB);
    vq_kernel<<<grid, 256, 0, stream>>>(mu, dict, z, zq, oh);
}